// Round 4
// baseline (246.208 us; speedup 1.0000x reference)
//
#include <hip/hip_runtime.h>
#include <hip/hip_bf16.h>

// B=4, C=256, N=HW=4096, Dqk=32.
// Round 12: R11 accounting showed matrix pipe 576 cyc/SIMD/body AND LDS pipe
// 576 cyc/CU/body, each ~28% busy -> the two pipes serialize (post-barrier
// ds_read burst drains LDS while matrix idles, then MFMAs drain while LDS
// idles, then S-chain + 2 barriers). Time tracked LDS-conflict cycles 1:1,
// NOT vector bytes. Fixes: (a) PV waves own (q-half 32q x 64ch): P-reads
// halve to 32KB/body (V tile loaded 2x -> 80KB vector/body, proven cheap in
// R8/R9); (b) 4-deep P buffer, ONE barrier per 2 bodies: S runs 2-3 tiles
// ahead, PV's body-J+1 ds_reads overlap body-J MFMAs, barriers halve.
// Carried: wave specialization, conflict-free 16B-slot P layout, x2 unroll
// named reg sets, SGPR-base addressing, &63 wrap prefetch, packed-Vp, S^T
// trick, LDS-only barrier, XCD swizzle, packed-W qkv, no-max softmax.

#define N_PIX 4096
#define DQK   32
#define CCH   256
#define LOG2E 1.44269504088896f

typedef __attribute__((ext_vector_type(8))) _Float16 f16x8;
typedef __attribute__((ext_vector_type(4))) _Float16 f16x4;
typedef __attribute__((ext_vector_type(2))) _Float16 f16x2;
typedef __attribute__((ext_vector_type(8))) short    bf16x8;
typedef __attribute__((ext_vector_type(4))) short    bf16x4;
typedef __attribute__((ext_vector_type(4))) float    f32x4;

// LDS-only block barrier: waits lgkmcnt(0) but leaves vmcnt untouched.
__device__ inline void barrier_lds() {
    asm volatile("" ::: "memory");
    __builtin_amdgcn_s_waitcnt(0xc07f);   // vmcnt=63, expcnt=7, lgkmcnt=0
    __builtin_amdgcn_s_barrier();
    asm volatile("" ::: "memory");
}

// pack two f32 -> two bf16 in one instruction (RNE)
__device__ inline unsigned cvt_pk_bf16(float lo, float hi) {
    unsigned r;
    asm("v_cvt_pk_bf16_f32 %0, %1, %2" : "=v"(r) : "v"(lo), "v"(hi));
    return r;
}

// ---------------------------------------------------------------------------
// Kernel 0: pack Wq|Wk|Wv -> f16 A-fragments, lane-ordered (LOG2E folded into Wq).
// ---------------------------------------------------------------------------
__global__ __launch_bounds__(256) void wpack_kernel(
    const float* __restrict__ Wq, const float* __restrict__ Wk,
    const float* __restrict__ Wv, _Float16* __restrict__ Wp)
{
    const int tid   = threadIdx.x;
    const int wflat = blockIdx.x * 4 + (tid >> 6);   // 0..159
    const int lane  = tid & 63;
    const int L15   = lane & 15;
    const int quad  = lane >> 4;
    const int mt    = wflat >> 3;
    const int ks    = wflat & 7;
    const int m0    = mt * 16;

    const float* Wsrc; int row; float scale = 1.f;
    if (m0 < 32)      { Wsrc = Wq; row = m0 + L15;      scale = LOG2E; }
    else if (m0 < 64) { Wsrc = Wk; row = m0 - 32 + L15; }
    else              { Wsrc = Wv; row = m0 - 64 + L15; }

    const float* p = Wsrc + (size_t)row * 256 + ks * 32 + quad * 8;
    f16x8 h;
    #pragma unroll
    for (int j = 0; j < 8; ++j) h[j] = (_Float16)(p[j] * scale);
    *(f16x8*)(Wp + ((size_t)wflat * 64 + lane) * 8) = h;
}

// ---------------------------------------------------------------------------
// Kernel 1: QKV projection, f16 MFMA, packed W. Grid 512, 512 thr = 8 waves,
// 32-pixel tiles. V output goes through LDS transpose -> packed B-frag layout:
//   Vp[b][(n0>>5)*16 + cg16][lane(quad,L15)][j] = v[cg16*16+L15][n0 + quad*8+j]
// ---------------------------------------------------------------------------
__global__ __launch_bounds__(512, 4) void qkv_kernel(
    const float* __restrict__ x, const _Float16* __restrict__ Wp,
    const float* __restrict__ bq, const float* __restrict__ bk,
    const float* __restrict__ bv,
    _Float16* __restrict__ qo, _Float16* __restrict__ ko,
    __hip_bfloat16* __restrict__ vp)
{
    // shared: xT (32x264 f16 = 16.9KB) then reused as vst (256x40 bf16 = 20KB)
    __shared__ alignas(16) unsigned char shraw[256 * 40 * 2];
    _Float16       (*xT)[264] = (_Float16 (*)[264])shraw;
    __hip_bfloat16 (*vst)[40] = (__hip_bfloat16 (*)[40])shraw;

    const int idx = blockIdx.x;
    const int b   = (idx & 7) >> 1;
    const int n0  = (((idx >> 3) << 1) | (idx & 1)) * 32;
    const int tid = threadIdx.x;

    // stage x[256c][32n] -> xT[n][c] f16
    {
        const float* xb = x + (size_t)b * CCH * N_PIX;
        float4 ld[2][2];
        int c2s[2], n4s[2];
        #pragma unroll
        for (int pass = 0; pass < 2; ++pass) {
            const int flat = pass * 512 + tid;
            c2s[pass] = (flat >> 3) * 2;
            n4s[pass] = (flat & 7) * 4;
            ld[pass][0] = *(const float4*)(xb + (size_t)c2s[pass]       * N_PIX + n0 + n4s[pass]);
            ld[pass][1] = *(const float4*)(xb + (size_t)(c2s[pass] + 1) * N_PIX + n0 + n4s[pass]);
        }
        #pragma unroll
        for (int pass = 0; pass < 2; ++pass) {
            const float a[4] = {ld[pass][0].x, ld[pass][0].y, ld[pass][0].z, ld[pass][0].w};
            const float c[4] = {ld[pass][1].x, ld[pass][1].y, ld[pass][1].z, ld[pass][1].w};
            #pragma unroll
            for (int i = 0; i < 4; ++i)
                *(f16x2*)(&xT[n4s[pass] + i][c2s[pass]]) =
                    (f16x2){(_Float16)a[i], (_Float16)c[i]};
        }
    }
    __syncthreads();

    const int lane = tid & 63;
    const int wid  = tid >> 6;
    const int L15  = lane & 15;
    const int quad = lane >> 4;
    const int nf   = wid & 1;
    const int mtg  = wid >> 1;

    const f32x4 fz = {0.f, 0.f, 0.f, 0.f};
    f32x4 acc[5];
    #pragma unroll
    for (int mt = 0; mt < 5; ++mt) acc[mt] = fz;

    const _Float16* wpw = Wp + ((size_t)(mtg * 5) * 8 * 64 + lane) * 8;

    #pragma unroll
    for (int ks = 0; ks < 8; ++ks) {
        const f16x8 bfr = *(const f16x8*)(&xT[nf * 16 + L15][ks * 32 + quad * 8]);
        #pragma unroll
        for (int mt = 0; mt < 5; ++mt) {
            const f16x8 afr = *(const f16x8*)(wpw + (size_t)(mt * 8 + ks) * 512);
            acc[mt] = __builtin_amdgcn_mfma_f32_16x16x32_f16(afr, bfr, acc[mt], 0, 0, 0);
        }
    }

    // q/k epilogue (global, no LDS): C/D row = out-row (quad*4+r), col = pixel (L15)
    const int np = nf * 16 + L15;         // local pixel 0..31
    const int n  = n0 + np;
    #pragma unroll
    for (int mt = 0; mt < 5; ++mt) {
        const int m0 = (mtg * 5 + mt) * 16;
        const f32x4 a = acc[mt];
        if (m0 < 32) {
            const int mr = m0 + quad * 4;
            f16x4 h;
            #pragma unroll
            for (int r = 0; r < 4; ++r) h[r] = (_Float16)(a[r] + bq[mr + r] * LOG2E);
            *(f16x4*)(qo + ((size_t)b * N_PIX + n) * DQK + mr) = h;
        } else if (m0 < 64) {
            const int mr = m0 - 32 + quad * 4;
            f16x4 h;
            #pragma unroll
            for (int r = 0; r < 4; ++r) h[r] = (_Float16)(a[r] + bk[mr + r]);
            *(f16x4*)(ko + ((size_t)b * N_PIX + n) * DQK + mr) = h;
        }
    }

    __syncthreads();   // xT dead; vst aliases it

    // v -> LDS transpose buffer vst[ch][pix] (rows padded to 40 elems, 16B-aligned)
    #pragma unroll
    for (int mt = 0; mt < 5; ++mt) {
        const int m0 = (mtg * 5 + mt) * 16;
        if (m0 >= 64) {
            const int c = m0 - 64 + quad * 4;
            #pragma unroll
            for (int r = 0; r < 4; ++r)
                vst[c + r][np] = __float2bfloat16(acc[mt][r] + bv[c + r]);
        }
    }
    __syncthreads();

    // packed store: slot (cg16, lane'=(qd,l15)) -> one b128 LDS read + one 16B store
    {
        __hip_bfloat16* vpb = vp + (size_t)b * 2048 * 512 + (size_t)((n0 >> 5) * 16) * 512;
        #pragma unroll
        for (int s = 0; s < 2; ++s) {
            const int slot = s * 512 + tid;   // 0..1023
            const int cg16 = slot >> 6;
            const int ln   = slot & 63;
            const int qd   = ln >> 4;
            const int l15  = ln & 15;
            const bf16x8 val = *(const bf16x8*)(&vst[cg16 * 16 + l15][qd * 8]);
            *(bf16x8*)(vpb + ((size_t)cg16 * 64 + ln) * 8) = val;
        }
    }
}

// ---------------------------------------------------------------------------
// Kernel 2: attention. Grid 256 (XCD-swizzled), 1024 threads = 16 waves,
// 64 queries per block, 1 block/CU. Wave-specialized, 4-deep P pipeline:
//   PV waves (wid 0..7): (qh=wid&1, cgrp=wid>>1) owns 32 queries x 64 ch.
//     Per body: 4 contiguous-1KB Ps reads + 16 MFMA + 8 V chunk loads.
//   S waves (wid 8..15): group g = wid-8 (16q x 32k P tile); runs 2-3 bodies
//     AHEAD of PV: during window {J,J+1} computes/writes P(J+2), P(J+3).
//   ONE barrier per 2 bodies; P(J) lives in buf J&3 (disjoint read/write sets
//   each window). Body-(J+1) ds_reads overlap body-J MFMAs.
// P layout: Ps[buf][g][kb8][L15][8e] (16B slots): PV reads 1KB contiguous
// (0 conflicts), S uint2 writes 4/bank balanced.
// ---------------------------------------------------------------------------

#define PV_BODY(J, VR)                                                            \
  {                                                                               \
    const int buf_ = (J) & 3;                                                     \
    _Pragma("unroll")                                                             \
    for (int q2_ = 0; q2_ < 2; ++q2_) {                                           \
      _Pragma("unroll")                                                           \
      for (int kk_ = 0; kk_ < 2; ++kk_) {                                         \
        const bf16x8 ap_ = *(const bf16x8*)(                                      \
            &Ps[buf_][(qh * 2 + q2_) * 2 + kk_][quad][L15][0]);                   \
        _Pragma("unroll")                                                         \
        for (int cf_ = 0; cf_ < 4; ++cf_)                                         \
          oacc[q2_][cf_] = __builtin_amdgcn_mfma_f32_16x16x32_bf16(               \
              ap_, VR[kk_][cf_], oacc[q2_][cf_], 0, 0, 0);                        \
      }                                                                           \
    }                                                                             \
    const __hip_bfloat16* vt_ = vb + (size_t)(((J) + 2) & 63) * 16384;            \
    _Pragma("unroll")                                                             \
    for (int kk_ = 0; kk_ < 2; ++kk_)                                             \
      _Pragma("unroll")                                                           \
      for (int cf_ = 0; cf_ < 4; ++cf_)                                           \
        VR[kk_][cf_] = *(const bf16x8*)(vt_ + voffW + kk_ * 8192 + cf_ * 512);    \
  }

// One body's S work for this wave's group: 2 S-MFMA + 8 exp2 + 2 uint2 writes.
#define S_TILE(KR0, KR1, BUF)                                                     \
  {                                                                               \
    const f32x4 s0_ = __builtin_amdgcn_mfma_f32_16x16x32_f16(KR0, aq, fz, 0, 0, 0); \
    const f32x4 s1_ = __builtin_amdgcn_mfma_f32_16x16x32_f16(KR1, aq, fz, 0, 0, 0); \
    const float a0_ = exp2f(s0_[0]), a1_ = exp2f(s0_[1]);                         \
    const float a2_ = exp2f(s0_[2]), a3_ = exp2f(s0_[3]);                         \
    psum0 += (a0_ + a1_) + (a2_ + a3_);                                           \
    uint2 w0_; w0_.x = cvt_pk_bf16(a0_, a1_); w0_.y = cvt_pk_bf16(a2_, a3_);      \
    *(uint2*)(&Ps[BUF][grp][quad >> 1][L15][(quad & 1) * 4]) = w0_;               \
    const float b0_ = exp2f(s1_[0]), b1_ = exp2f(s1_[1]);                         \
    const float b2_ = exp2f(s1_[2]), b3_ = exp2f(s1_[3]);                         \
    psum1 += (b0_ + b1_) + (b2_ + b3_);                                           \
    uint2 w1_; w1_.x = cvt_pk_bf16(b0_, b1_); w1_.y = cvt_pk_bf16(b2_, b3_);      \
    *(uint2*)(&Ps[BUF][grp][2 + (quad >> 1)][L15][(quad & 1) * 4]) = w1_;         \
  }

__global__ __launch_bounds__(1024, 4) void attn_kernel(
    const _Float16* __restrict__ qg,        // [B][N][32], q pre-scaled by log2e
    const _Float16* __restrict__ kg,        // [B][N][32]
    const __hip_bfloat16* __restrict__ vp,  // packed: [B][2048 chunks][64][8]
    float* __restrict__ out)                // [B][C][N]
{
    __shared__ __hip_bfloat16 Ps[4][8][4][16][8];   // 32KB; [buf][g][kb8][L15][e]
    __shared__ float lsum[4][4][16];                // [qt][kt][query]

    const int idx  = blockIdx.x;
    const int b    = (idx & 7) >> 1;
    const int n0   = (((idx >> 3) << 1) | (idx & 1)) * 64;
    const int tid  = threadIdx.x;
    const int wid  = tid >> 6;
    const int lane = tid & 63;
    const int L15  = lane & 15;
    const int quad = lane >> 4;
    const bool is_pv = (wid < 8);

    const f32x4 fz = {0.f, 0.f, 0.f, 0.f};

    // ---- PV-wave state (wid 0..7): q-half x 64-channel group
    const int qh   = wid & 1;
    const int cgrp = wid >> 1;                     // 0..3
    const __hip_bfloat16* vb = vp + (size_t)b * 2048 * 512;
    const int voffW = lane * 8 + (cgrp * 4) * 512; // + kk*8192 + cf*512
    f32x4 oacc[2][4];
    #pragma unroll
    for (int q2 = 0; q2 < 2; ++q2)
        #pragma unroll
        for (int cf = 0; cf < 4; ++cf) oacc[q2][cf] = fz;
    bf16x8 vA[2][4], vB[2][4];

    // ---- S-wave state (wid 8..15): group g = s; tiles (qt=s>>1, kt=2(s&1)+{0,1})
    const int sqt  = (wid & 7) >> 1;
    const int kt0  = (wid & 1) * 2;
    const int grp  = wid & 7;
    const _Float16* kbp = kg + (size_t)b * N_PIX * DQK;
    const int koff0 = ((kt0 + 0) * 16 + L15) * DQK + quad * 8;
    const int koff1 = ((kt0 + 1) * 16 + L15) * DQK + quad * 8;
    f16x8 aq{}, kA0{}, kA1{}, kB0{}, kB1{};
    float psum0 = 0.f, psum1 = 0.f;

    // ---- prologue: PV loads V(0),V(1); S computes P(0),P(1), preloads K(2),K(3)
    if (is_pv) {
        #pragma unroll
        for (int kk = 0; kk < 2; ++kk)
            #pragma unroll
            for (int cf = 0; cf < 4; ++cf) {
                vA[kk][cf] = *(const bf16x8*)(vb +         voffW + kk * 8192 + cf * 512);
                vB[kk][cf] = *(const bf16x8*)(vb + 16384 + voffW + kk * 8192 + cf * 512);
            }
    } else {
        aq = *(const f16x8*)(qg + ((size_t)b * N_PIX + n0 + sqt * 16 + L15) * DQK + quad * 8);
        {
            const f16x8 k00 = *(const f16x8*)(kbp + koff0);
            const f16x8 k01 = *(const f16x8*)(kbp + koff1);
            S_TILE(k00, k01, 0)
        }
        {
            const f16x8 k10 = *(const f16x8*)(kbp + (size_t)64 * DQK + koff0);
            const f16x8 k11 = *(const f16x8*)(kbp + (size_t)64 * DQK + koff1);
            S_TILE(k10, k11, 1)
        }
        kA0 = *(const f16x8*)(kbp + (size_t)2 * 64 * DQK + koff0);
        kA1 = *(const f16x8*)(kbp + (size_t)2 * 64 * DQK + koff1);
        kB0 = *(const f16x8*)(kbp + (size_t)3 * 64 * DQK + koff0);
        kB1 = *(const f16x8*)(kbp + (size_t)3 * 64 * DQK + koff1);
    }
    barrier_lds();

    // ---- main loop: 32 windows of 2 bodies, ONE barrier per window.
    // Window J: PV consumes P(J),P(J+1) (bufs J&3,(J+1)&3);
    //           S produces P(J+2),P(J+3) (bufs (J+2)&3,(J+3)&3) -- disjoint.
    for (int it = 0; it < 64; it += 2) {
        if (is_pv) {
            PV_BODY(it,     vA)
            PV_BODY(it + 1, vB)
        } else if (it < 62) {
            S_TILE(kA0, kA1, (it + 2) & 3)
            {
                const _Float16* kp = kbp + (size_t)((it + 4) & 63) * (64 * DQK);
                kA0 = *(const f16x8*)(kp + koff0);
                kA1 = *(const f16x8*)(kp + koff1);
            }
            S_TILE(kB0, kB1, (it + 3) & 3)
            {
                const _Float16* kp = kbp + (size_t)((it + 5) & 63) * (64 * DQK);
                kB0 = *(const f16x8*)(kp + koff0);
                kB1 = *(const f16x8*)(kp + koff1);
            }
        }
        barrier_lds();
    }

    // ---- epilogue: S waves publish row-sums, PV waves normalize + store
    if (!is_pv) {
        psum0 += __shfl_xor(psum0, 16, 64);
        psum0 += __shfl_xor(psum0, 32, 64);
        psum1 += __shfl_xor(psum1, 16, 64);
        psum1 += __shfl_xor(psum1, 32, 64);
        if (quad == 0) {
            lsum[sqt][kt0 + 0][L15] = psum0;
            lsum[sqt][kt0 + 1][L15] = psum1;
        }
    }
    __syncthreads();

    if (is_pv) {
        float* ob = out + (size_t)b * CCH * N_PIX;
        #pragma unroll
        for (int q2 = 0; q2 < 2; ++q2) {
            const int qtile = qh * 2 + q2;
            float inv_l[4];
            #pragma unroll
            for (int r = 0; r < 4; ++r) {
                const int q = quad * 4 + r;
                inv_l[r] = 1.f / (lsum[qtile][0][q] + lsum[qtile][1][q] +
                                  lsum[qtile][2][q] + lsum[qtile][3][q]);
            }
            #pragma unroll
            for (int cf = 0; cf < 4; ++cf) {
                const int c = cgrp * 64 + cf * 16 + L15;
                f32x4 o;
                #pragma unroll
                for (int r = 0; r < 4; ++r) o[r] = oacc[q2][cf][r] * inv_l[r];
                *(f32x4*)(ob + (size_t)c * N_PIX + n0 + qtile * 16 + quad * 4) = o;
            }
        }
    }
}

// ---------------------------------------------------------------------------
extern "C" void kernel_launch(void* const* d_in, const int* in_sizes, int n_in,
                              void* d_out, int out_size, void* d_ws, size_t ws_size,
                              hipStream_t stream) {
    (void)in_sizes; (void)n_in; (void)out_size; (void)ws_size;
    const float* x  = (const float*)d_in[0];
    const float* Wq = (const float*)d_in[1];
    const float* bq = (const float*)d_in[2];
    const float* Wk = (const float*)d_in[3];
    const float* bk = (const float*)d_in[4];
    const float* Wv = (const float*)d_in[5];
    const float* bv = (const float*)d_in[6];

    // workspace: q 1MB | k 1MB | Vp 8MB | Wp 160KB
    _Float16* qb = (_Float16*)d_ws;
    _Float16* kb = qb + (size_t)4 * N_PIX * DQK;
    __hip_bfloat16* vpk = (__hip_bfloat16*)(kb + (size_t)4 * N_PIX * DQK);
    _Float16* wp = (_Float16*)(vpk + (size_t)4 * 2048 * 512);
    float* outp = (float*)d_out;

    wpack_kernel<<<40, 256, 0, stream>>>(Wq, Wk, Wv, wp);
    qkv_kernel<<<512, 512, 0, stream>>>(x, wp, bq, bk, bv, qb, kb, vpk);
    attn_kernel<<<256, 1024, 0, stream>>>(qb, kb, vpk, outp);
}

// Round 5
// 136.323 us; speedup vs baseline: 1.8061x; 1.8061x over previous
//
#include <hip/hip_runtime.h>
#include <hip/hip_bf16.h>

// B=4, C=256, N=HW=4096, Dqk=32.
// Round 13: R12 regressed 3x from VGPR spill (WRITE_SIZE 16->250MB scratch):
// the 64ch PV mapping needed ~110 VGPRs against a 64-reg clamp. Pipeline test
// was poisoned. R13 = R11 register footprint (PV owns 64q x 32ch, ~60 VGPR)
// + ONLY the scheduling changes: (a) 4-deep P buffer, ONE barrier per 2-body
// window (S runs 2 bodies ahead, disjoint buf pairs each window; body-J+1
// ds_reads overlap body-J MFMAs); (b) s_setprio(1) around PV MFMA cluster
// (producer/consumer role split = the regime where setprio pays);
// (c) plain __launch_bounds__(1024) -> 128-reg cap, no spill.
// Carried: wave specialization, conflict-free 16B-slot P layout, x2 unroll
// named reg sets, SGPR-base addressing, &63 wrap prefetch, packed-Vp, S^T
// trick, LDS-only barrier, XCD swizzle, packed-W qkv, no-max softmax.

#define N_PIX 4096
#define DQK   32
#define CCH   256
#define LOG2E 1.44269504088896f

typedef __attribute__((ext_vector_type(8))) _Float16 f16x8;
typedef __attribute__((ext_vector_type(4))) _Float16 f16x4;
typedef __attribute__((ext_vector_type(2))) _Float16 f16x2;
typedef __attribute__((ext_vector_type(8))) short    bf16x8;
typedef __attribute__((ext_vector_type(4))) short    bf16x4;
typedef __attribute__((ext_vector_type(4))) float    f32x4;

// LDS-only block barrier: waits lgkmcnt(0) but leaves vmcnt untouched.
__device__ inline void barrier_lds() {
    asm volatile("" ::: "memory");
    __builtin_amdgcn_s_waitcnt(0xc07f);   // vmcnt=63, expcnt=7, lgkmcnt=0
    __builtin_amdgcn_s_barrier();
    asm volatile("" ::: "memory");
}

// pack two f32 -> two bf16 in one instruction (RNE)
__device__ inline unsigned cvt_pk_bf16(float lo, float hi) {
    unsigned r;
    asm("v_cvt_pk_bf16_f32 %0, %1, %2" : "=v"(r) : "v"(lo), "v"(hi));
    return r;
}

// ---------------------------------------------------------------------------
// Kernel 0: pack Wq|Wk|Wv -> f16 A-fragments, lane-ordered (LOG2E folded into Wq).
// ---------------------------------------------------------------------------
__global__ __launch_bounds__(256) void wpack_kernel(
    const float* __restrict__ Wq, const float* __restrict__ Wk,
    const float* __restrict__ Wv, _Float16* __restrict__ Wp)
{
    const int tid   = threadIdx.x;
    const int wflat = blockIdx.x * 4 + (tid >> 6);   // 0..159
    const int lane  = tid & 63;
    const int L15   = lane & 15;
    const int quad  = lane >> 4;
    const int mt    = wflat >> 3;
    const int ks    = wflat & 7;
    const int m0    = mt * 16;

    const float* Wsrc; int row; float scale = 1.f;
    if (m0 < 32)      { Wsrc = Wq; row = m0 + L15;      scale = LOG2E; }
    else if (m0 < 64) { Wsrc = Wk; row = m0 - 32 + L15; }
    else              { Wsrc = Wv; row = m0 - 64 + L15; }

    const float* p = Wsrc + (size_t)row * 256 + ks * 32 + quad * 8;
    f16x8 h;
    #pragma unroll
    for (int j = 0; j < 8; ++j) h[j] = (_Float16)(p[j] * scale);
    *(f16x8*)(Wp + ((size_t)wflat * 64 + lane) * 8) = h;
}

// ---------------------------------------------------------------------------
// Kernel 1: QKV projection, f16 MFMA, packed W. Grid 512, 512 thr = 8 waves,
// 32-pixel tiles. V output goes through LDS transpose -> packed B-frag layout:
//   Vp[b][(n0>>5)*16 + cg16][lane(quad,L15)][j] = v[cg16*16+L15][n0 + quad*8+j]
// ---------------------------------------------------------------------------
__global__ __launch_bounds__(512, 4) void qkv_kernel(
    const float* __restrict__ x, const _Float16* __restrict__ Wp,
    const float* __restrict__ bq, const float* __restrict__ bk,
    const float* __restrict__ bv,
    _Float16* __restrict__ qo, _Float16* __restrict__ ko,
    __hip_bfloat16* __restrict__ vp)
{
    // shared: xT (32x264 f16 = 16.9KB) then reused as vst (256x40 bf16 = 20KB)
    __shared__ alignas(16) unsigned char shraw[256 * 40 * 2];
    _Float16       (*xT)[264] = (_Float16 (*)[264])shraw;
    __hip_bfloat16 (*vst)[40] = (__hip_bfloat16 (*)[40])shraw;

    const int idx = blockIdx.x;
    const int b   = (idx & 7) >> 1;
    const int n0  = (((idx >> 3) << 1) | (idx & 1)) * 32;
    const int tid = threadIdx.x;

    // stage x[256c][32n] -> xT[n][c] f16
    {
        const float* xb = x + (size_t)b * CCH * N_PIX;
        float4 ld[2][2];
        int c2s[2], n4s[2];
        #pragma unroll
        for (int pass = 0; pass < 2; ++pass) {
            const int flat = pass * 512 + tid;
            c2s[pass] = (flat >> 3) * 2;
            n4s[pass] = (flat & 7) * 4;
            ld[pass][0] = *(const float4*)(xb + (size_t)c2s[pass]       * N_PIX + n0 + n4s[pass]);
            ld[pass][1] = *(const float4*)(xb + (size_t)(c2s[pass] + 1) * N_PIX + n0 + n4s[pass]);
        }
        #pragma unroll
        for (int pass = 0; pass < 2; ++pass) {
            const float a[4] = {ld[pass][0].x, ld[pass][0].y, ld[pass][0].z, ld[pass][0].w};
            const float c[4] = {ld[pass][1].x, ld[pass][1].y, ld[pass][1].z, ld[pass][1].w};
            #pragma unroll
            for (int i = 0; i < 4; ++i)
                *(f16x2*)(&xT[n4s[pass] + i][c2s[pass]]) =
                    (f16x2){(_Float16)a[i], (_Float16)c[i]};
        }
    }
    __syncthreads();

    const int lane = tid & 63;
    const int wid  = tid >> 6;
    const int L15  = lane & 15;
    const int quad = lane >> 4;
    const int nf   = wid & 1;
    const int mtg  = wid >> 1;

    const f32x4 fz = {0.f, 0.f, 0.f, 0.f};
    f32x4 acc[5];
    #pragma unroll
    for (int mt = 0; mt < 5; ++mt) acc[mt] = fz;

    const _Float16* wpw = Wp + ((size_t)(mtg * 5) * 8 * 64 + lane) * 8;

    #pragma unroll
    for (int ks = 0; ks < 8; ++ks) {
        const f16x8 bfr = *(const f16x8*)(&xT[nf * 16 + L15][ks * 32 + quad * 8]);
        #pragma unroll
        for (int mt = 0; mt < 5; ++mt) {
            const f16x8 afr = *(const f16x8*)(wpw + (size_t)(mt * 8 + ks) * 512);
            acc[mt] = __builtin_amdgcn_mfma_f32_16x16x32_f16(afr, bfr, acc[mt], 0, 0, 0);
        }
    }

    // q/k epilogue (global, no LDS): C/D row = out-row (quad*4+r), col = pixel (L15)
    const int np = nf * 16 + L15;         // local pixel 0..31
    const int n  = n0 + np;
    #pragma unroll
    for (int mt = 0; mt < 5; ++mt) {
        const int m0 = (mtg * 5 + mt) * 16;
        const f32x4 a = acc[mt];
        if (m0 < 32) {
            const int mr = m0 + quad * 4;
            f16x4 h;
            #pragma unroll
            for (int r = 0; r < 4; ++r) h[r] = (_Float16)(a[r] + bq[mr + r] * LOG2E);
            *(f16x4*)(qo + ((size_t)b * N_PIX + n) * DQK + mr) = h;
        } else if (m0 < 64) {
            const int mr = m0 - 32 + quad * 4;
            f16x4 h;
            #pragma unroll
            for (int r = 0; r < 4; ++r) h[r] = (_Float16)(a[r] + bk[mr + r]);
            *(f16x4*)(ko + ((size_t)b * N_PIX + n) * DQK + mr) = h;
        }
    }

    __syncthreads();   // xT dead; vst aliases it

    // v -> LDS transpose buffer vst[ch][pix] (rows padded to 40 elems, 16B-aligned)
    #pragma unroll
    for (int mt = 0; mt < 5; ++mt) {
        const int m0 = (mtg * 5 + mt) * 16;
        if (m0 >= 64) {
            const int c = m0 - 64 + quad * 4;
            #pragma unroll
            for (int r = 0; r < 4; ++r)
                vst[c + r][np] = __float2bfloat16(acc[mt][r] + bv[c + r]);
        }
    }
    __syncthreads();

    // packed store: slot (cg16, lane'=(qd,l15)) -> one b128 LDS read + one 16B store
    {
        __hip_bfloat16* vpb = vp + (size_t)b * 2048 * 512 + (size_t)((n0 >> 5) * 16) * 512;
        #pragma unroll
        for (int s = 0; s < 2; ++s) {
            const int slot = s * 512 + tid;   // 0..1023
            const int cg16 = slot >> 6;
            const int ln   = slot & 63;
            const int qd   = ln >> 4;
            const int l15  = ln & 15;
            const bf16x8 val = *(const bf16x8*)(&vst[cg16 * 16 + l15][qd * 8]);
            *(bf16x8*)(vpb + ((size_t)cg16 * 64 + ln) * 8) = val;
        }
    }
}

// ---------------------------------------------------------------------------
// Kernel 2: attention. Grid 256 (XCD-swizzled), 1024 threads = 16 waves,
// 64 queries per block, 1 block/CU. Wave-specialized, 4-deep P pipeline,
// ONE barrier per 2-body window:
//   PV waves (wid 0..7): cg = wid owns 32 channels x all 64 queries.
//     Per body: 8 contiguous-1KB Ps reads + 16 MFMA (setprio-wrapped) + 4 V
//     chunk loads. V register footprint = R11's (32 VGPR).
//   S waves (wid 8..15): group g = wid-8; runs 2 bodies AHEAD: during window
//     {J,J+1} computes/writes P(J+2),P(J+3) into bufs {(J+2)&3,(J+3)&3}
//     (disjoint from PV's read bufs {J&3,(J+1)&3}).
// P layout: Ps[buf][g][kb8][L15][8e] (16B slots): PV reads 1KB contiguous
// (0 conflicts), S uint2 writes 4/bank balanced.
// ---------------------------------------------------------------------------

#define PV_BODY(J, VR)                                                            \
  {                                                                               \
    const int buf_ = (J) & 3;                                                     \
    __builtin_amdgcn_s_setprio(1);                                                \
    _Pragma("unroll")                                                             \
    for (int qq_ = 0; qq_ < 4; ++qq_) {                                           \
      _Pragma("unroll")                                                           \
      for (int kk_ = 0; kk_ < 2; ++kk_) {                                         \
        const bf16x8 ap_ = *(const bf16x8*)(&Ps[buf_][qq_ * 2 + kk_][quad][L15][0]); \
        oacc[qq_][0] = __builtin_amdgcn_mfma_f32_16x16x32_bf16(                   \
            ap_, VR[kk_][0], oacc[qq_][0], 0, 0, 0);                              \
        oacc[qq_][1] = __builtin_amdgcn_mfma_f32_16x16x32_bf16(                   \
            ap_, VR[kk_][1], oacc[qq_][1], 0, 0, 0);                              \
      }                                                                           \
    }                                                                             \
    __builtin_amdgcn_s_setprio(0);                                                \
    const __hip_bfloat16* vt_ = vb + (size_t)(((J) + 2) & 63) * 16384;            \
    _Pragma("unroll")                                                             \
    for (int kk_ = 0; kk_ < 2; ++kk_)                                             \
      _Pragma("unroll")                                                           \
      for (int cf_ = 0; cf_ < 2; ++cf_)                                           \
        VR[kk_][cf_] = *(const bf16x8*)(vt_ + voff0 + kk_ * 8192 + cf_ * 512);    \
  }

// One body's S work for this wave's group: 2 S-MFMA + 8 exp2 + 2 uint2 writes.
#define S_TILE(KR0, KR1, BUF)                                                     \
  {                                                                               \
    const f32x4 s0_ = __builtin_amdgcn_mfma_f32_16x16x32_f16(KR0, aq, fz, 0, 0, 0); \
    const f32x4 s1_ = __builtin_amdgcn_mfma_f32_16x16x32_f16(KR1, aq, fz, 0, 0, 0); \
    const float a0_ = exp2f(s0_[0]), a1_ = exp2f(s0_[1]);                         \
    const float a2_ = exp2f(s0_[2]), a3_ = exp2f(s0_[3]);                         \
    psum0 += (a0_ + a1_) + (a2_ + a3_);                                           \
    uint2 w0_; w0_.x = cvt_pk_bf16(a0_, a1_); w0_.y = cvt_pk_bf16(a2_, a3_);      \
    *(uint2*)(&Ps[BUF][grp][quad >> 1][L15][(quad & 1) * 4]) = w0_;               \
    const float b0_ = exp2f(s1_[0]), b1_ = exp2f(s1_[1]);                         \
    const float b2_ = exp2f(s1_[2]), b3_ = exp2f(s1_[3]);                         \
    psum1 += (b0_ + b1_) + (b2_ + b3_);                                           \
    uint2 w1_; w1_.x = cvt_pk_bf16(b0_, b1_); w1_.y = cvt_pk_bf16(b2_, b3_);      \
    *(uint2*)(&Ps[BUF][grp][2 + (quad >> 1)][L15][(quad & 1) * 4]) = w1_;         \
  }

__global__ __launch_bounds__(1024) void attn_kernel(
    const _Float16* __restrict__ qg,        // [B][N][32], q pre-scaled by log2e
    const _Float16* __restrict__ kg,        // [B][N][32]
    const __hip_bfloat16* __restrict__ vp,  // packed: [B][2048 chunks][64][8]
    float* __restrict__ out)                // [B][C][N]
{
    __shared__ __hip_bfloat16 Ps[4][8][4][16][8];   // 32KB; [buf][g][kb8][L15][e]
    __shared__ float lsum[4][4][16];                // [qt][kt][query]

    const int idx  = blockIdx.x;
    const int b    = (idx & 7) >> 1;
    const int n0   = (((idx >> 3) << 1) | (idx & 1)) * 64;
    const int tid  = threadIdx.x;
    const int wid  = tid >> 6;
    const int lane = tid & 63;
    const int L15  = lane & 15;
    const int quad = lane >> 4;
    const bool is_pv = (wid < 8);

    const f32x4 fz = {0.f, 0.f, 0.f, 0.f};

    // ---- PV-wave state (wid 0..7): all 64 q x 32-channel group
    const int cg = wid & 7;
    const __hip_bfloat16* vb = vp + (size_t)b * 2048 * 512;
    const int voff0 = lane * 8 + cg * 2 * 512;     // + kk*8192 + cf*512
    f32x4 oacc[4][2];
    #pragma unroll
    for (int qq = 0; qq < 4; ++qq) { oacc[qq][0] = fz; oacc[qq][1] = fz; }
    bf16x8 vA[2][2], vB[2][2];

    // ---- S-wave state (wid 8..15): group g = s; tiles (qt=s>>1, kt=2(s&1)+{0,1})
    const int sqt  = (wid & 7) >> 1;
    const int kt0  = (wid & 1) * 2;
    const int grp  = wid & 7;
    const _Float16* kbp = kg + (size_t)b * N_PIX * DQK;
    const int koff0 = ((kt0 + 0) * 16 + L15) * DQK + quad * 8;
    const int koff1 = ((kt0 + 1) * 16 + L15) * DQK + quad * 8;
    f16x8 aq{}, kA0{}, kA1{}, kB0{}, kB1{};
    float psum0 = 0.f, psum1 = 0.f;

    // ---- prologue: PV loads V(0),V(1); S computes P(0),P(1), preloads K(2),K(3)
    if (is_pv) {
        #pragma unroll
        for (int kk = 0; kk < 2; ++kk)
            #pragma unroll
            for (int cf = 0; cf < 2; ++cf) {
                vA[kk][cf] = *(const bf16x8*)(vb +         voff0 + kk * 8192 + cf * 512);
                vB[kk][cf] = *(const bf16x8*)(vb + 16384 + voff0 + kk * 8192 + cf * 512);
            }
    } else {
        aq = *(const f16x8*)(qg + ((size_t)b * N_PIX + n0 + sqt * 16 + L15) * DQK + quad * 8);
        {
            const f16x8 k00 = *(const f16x8*)(kbp + koff0);
            const f16x8 k01 = *(const f16x8*)(kbp + koff1);
            S_TILE(k00, k01, 0)
        }
        {
            const f16x8 k10 = *(const f16x8*)(kbp + (size_t)64 * DQK + koff0);
            const f16x8 k11 = *(const f16x8*)(kbp + (size_t)64 * DQK + koff1);
            S_TILE(k10, k11, 1)
        }
        kA0 = *(const f16x8*)(kbp + (size_t)2 * 64 * DQK + koff0);
        kA1 = *(const f16x8*)(kbp + (size_t)2 * 64 * DQK + koff1);
        kB0 = *(const f16x8*)(kbp + (size_t)3 * 64 * DQK + koff0);
        kB1 = *(const f16x8*)(kbp + (size_t)3 * 64 * DQK + koff1);
    }
    barrier_lds();

    // ---- main loop: 32 windows of 2 bodies, ONE barrier per window.
    // Window J (J even): PV consumes P(J),P(J+1) (bufs J&3,(J+1)&3);
    //                    S produces P(J+2),P(J+3) (bufs (J+2)&3,(J+3)&3).
    for (int it = 0; it < 64; it += 2) {
        if (is_pv) {
            PV_BODY(it,     vA)
            PV_BODY(it + 1, vB)
        } else if (it < 62) {
            S_TILE(kA0, kA1, (it + 2) & 3)
            {
                const _Float16* kp = kbp + (size_t)((it + 4) & 63) * (64 * DQK);
                kA0 = *(const f16x8*)(kp + koff0);
                kA1 = *(const f16x8*)(kp + koff1);
            }
            S_TILE(kB0, kB1, (it + 3) & 3)
            {
                const _Float16* kp = kbp + (size_t)((it + 5) & 63) * (64 * DQK);
                kB0 = *(const f16x8*)(kp + koff0);
                kB1 = *(const f16x8*)(kp + koff1);
            }
        }
        barrier_lds();
    }

    // ---- epilogue: S waves publish row-sums, PV waves normalize + store
    if (!is_pv) {
        psum0 += __shfl_xor(psum0, 16, 64);
        psum0 += __shfl_xor(psum0, 32, 64);
        psum1 += __shfl_xor(psum1, 16, 64);
        psum1 += __shfl_xor(psum1, 32, 64);
        if (quad == 0) {
            lsum[sqt][kt0 + 0][L15] = psum0;
            lsum[sqt][kt0 + 1][L15] = psum1;
        }
    }
    __syncthreads();

    if (is_pv) {
        float* ob = out + (size_t)b * CCH * N_PIX;
        #pragma unroll
        for (int qq = 0; qq < 4; ++qq) {
            float inv_l[4];
            #pragma unroll
            for (int r = 0; r < 4; ++r) {
                const int q = quad * 4 + r;
                inv_l[r] = 1.f / (lsum[qq][0][q] + lsum[qq][1][q] +
                                  lsum[qq][2][q] + lsum[qq][3][q]);
            }
            #pragma unroll
            for (int cf = 0; cf < 2; ++cf) {
                const int c = cg * 32 + cf * 16 + L15;
                f32x4 o;
                #pragma unroll
                for (int r = 0; r < 4; ++r) o[r] = oacc[qq][cf][r] * inv_l[r];
                *(f32x4*)(ob + (size_t)c * N_PIX + n0 + qq * 16 + quad * 4) = o;
            }
        }
    }
}

// ---------------------------------------------------------------------------
extern "C" void kernel_launch(void* const* d_in, const int* in_sizes, int n_in,
                              void* d_out, int out_size, void* d_ws, size_t ws_size,
                              hipStream_t stream) {
    (void)in_sizes; (void)n_in; (void)out_size; (void)ws_size;
    const float* x  = (const float*)d_in[0];
    const float* Wq = (const float*)d_in[1];
    const float* bq = (const float*)d_in[2];
    const float* Wk = (const float*)d_in[3];
    const float* bk = (const float*)d_in[4];
    const float* Wv = (const float*)d_in[5];
    const float* bv = (const float*)d_in[6];

    // workspace: q 1MB | k 1MB | Vp 8MB | Wp 160KB
    _Float16* qb = (_Float16*)d_ws;
    _Float16* kb = qb + (size_t)4 * N_PIX * DQK;
    __hip_bfloat16* vpk = (__hip_bfloat16*)(kb + (size_t)4 * N_PIX * DQK);
    _Float16* wp = (_Float16*)(vpk + (size_t)4 * 2048 * 512);
    float* outp = (float*)d_out;

    wpack_kernel<<<40, 256, 0, stream>>>(Wq, Wk, Wv, wp);
    qkv_kernel<<<512, 512, 0, stream>>>(x, wp, bq, bk, bv, qb, kb, vpk);
    attn_kernel<<<256, 1024, 0, stream>>>(qb, kb, vpk, outp);
}